// Round 1
// 763.374 us; speedup vs baseline: 1.0233x; 1.0233x over previous
//
#include <hip/hip_runtime.h>
#include <hip/hip_bf16.h>

#define Bx 16
#define Cx 256
#define Hx 96
#define Wx 96
#define HWx 9216
#define NTOK 147456
#define Gx 16
#define GRPN 147456.0f

typedef unsigned short u16;
typedef unsigned int u32;
typedef __attribute__((ext_vector_type(8))) short short8;
typedef __attribute__((ext_vector_type(4))) float float4_;
typedef __attribute__((ext_vector_type(4))) unsigned short us4;
typedef __attribute__((ext_vector_type(8))) unsigned short us8;
typedef __attribute__((ext_vector_type(4))) unsigned int ui4;

__device__ __forceinline__ float b2f(u16 u){ u32 x = ((u32)u)<<16; float f; __builtin_memcpy(&f,&x,4); return f; }
__device__ __forceinline__ u16 f2b(float f){ u32 x; __builtin_memcpy(&x,&f,4); x += 0x7FFFu + ((x>>16)&1u); return (u16)(x>>16); }
__device__ __forceinline__ float sigm(float v){ return 1.0f/(1.0f+__expf(-v)); }

// ---------------- transpose x[b,c,hw] (fp32) -> xT[b,hw,c] (bf16) ----------------
__global__ __launch_bounds__(256) void k_transpose(const float* __restrict__ X, u16* __restrict__ XT){
  __shared__ u16 tile[32][36];
  int blk = blockIdx.x;
  int ct  = blk & 7;
  int hwt = (blk >> 3) % 288;
  int b   = blk / 2304;
  int c0 = ct*32, hw0 = hwt*32;
  int t = threadIdx.x;
  int r  = t >> 3;            // load: c-row   | store: hw-row
  int q4 = (t & 7) << 2;      // load: hw-off  | store: c-off
  float4_ v = *(const float4_*)&X[((size_t)(b*Cx + c0 + r))*HWx + hw0 + q4];
  tile[r][q4+0]=f2b(v[0]); tile[r][q4+1]=f2b(v[1]); tile[r][q4+2]=f2b(v[2]); tile[r][q4+3]=f2b(v[3]);
  __syncthreads();
  us4 o = { tile[q4+0][r], tile[q4+1][r], tile[q4+2][r], tile[q4+3][r] };
  *(us4*)&XT[((size_t)(b*HWx + hw0 + r))*Cx + c0 + q4] = o;
}

// ---------------- GEMM: Y[n,o] = sum_c A[n,c]*Wm[o,c]  (MFMA bf16, fp32 weights) ----------------
// MODE 0: store bf16 + groupnorm stats atomics. MODE 1: gate epilogue (sigmoid(+bias), fused=0.25*S*gate in-place).
#define BM 128
#define BN 64
#define LDA 40
#define LDB 264

template<int MODE>
__global__ __launch_bounds__(256) void k_gemm(const u16* __restrict__ A,
                                              const float* __restrict__ Wm,
                                              u16* __restrict__ Y,
                                              float* __restrict__ stats,
                                              const float* __restrict__ bias,
                                              u16* __restrict__ Sb)
{
  __shared__ u16 Ws[BN*LDB];
  __shared__ u16 As[BM*LDA];
  __shared__ float red[4][16][2];
  const int tid = threadIdx.x;
  const int n0 = blockIdx.x * BM;
  const int o0 = blockIdx.y * BN;
  // W panel (64 x 256) resident for whole K loop: fp32 -> bf16 convert on stage
  #pragma unroll
  for (int it=0; it<16; ++it){
    int cid = tid + it*256;        // 0..4095
    int row = cid >> 6;            // 0..63
    int ko  = (cid & 63) << 2;     // 0..252 step 4
    float4_ w4 = *(const float4_*)&Wm[(size_t)(o0+row)*Cx + ko];
    us4 wb = { f2b(w4[0]), f2b(w4[1]), f2b(w4[2]), f2b(w4[3]) };
    *(us4*)&Ws[row*LDB + ko] = wb;
  }
  const int lane = tid & 63;
  const int wid  = tid >> 6;
  const int lm   = lane & 15;
  const int quad = lane >> 4;
  const int wn = wid & 1;     // n offset 0/64
  const int wo = wid >> 1;    // o offset 0/32
  float4_ acc[4][2];
  #pragma unroll
  for (int i=0;i<4;++i){ acc[i][0] = (float4_)0.0f; acc[i][1] = (float4_)0.0f; }
  for (int kk=0; kk<Cx; kk+=32){
    __syncthreads();
    #pragma unroll
    for (int it=0; it<2; ++it){
      int cid = tid + it*256;
      int r = cid >> 2;
      int ko = (cid & 3) << 3;
      *(ui4*)&As[r*LDA + ko] = *(const ui4*)&A[(size_t)(n0+r)*Cx + kk + ko];
    }
    __syncthreads();
    short8 af[4], bf[2];
    #pragma unroll
    for (int i=0;i<4;++i) af[i] = *(const short8*)&As[(wn*64 + i*16 + lm)*LDA + quad*8];
    #pragma unroll
    for (int j=0;j<2;++j) bf[j] = *(const short8*)&Ws[(wo*32 + j*16 + lm)*LDB + kk + quad*8];
    #pragma unroll
    for (int i=0;i<4;++i)
      #pragma unroll
      for (int j=0;j<2;++j)
        acc[i][j] = __builtin_amdgcn_mfma_f32_16x16x32_bf16(af[i], bf[j], acc[i][j], 0, 0, 0);
  }
  const int b = n0 / HWx;
  if (MODE == 1){
    #pragma unroll
    for (int i=0;i<4;++i){
      #pragma unroll
      for (int j=0;j<2;++j){
        int oc = o0 + wo*32 + j*16 + lm;
        float bb = bias[oc];
        #pragma unroll
        for (int r=0;r<4;++r){
          int row = n0 + wn*64 + i*16 + quad*4 + r;
          size_t idx = (size_t)row*Cx + oc;
          float g = sigm(acc[i][j][r] + bb);
          Y[idx] = f2b(0.25f * b2f(Sb[idx]) * g);
        }
      }
    }
  } else {
    float s0=0,s1=0,q0=0,q1=0;
    #pragma unroll
    for (int i=0;i<4;++i){
      #pragma unroll
      for (int j=0;j<2;++j){
        int oc = o0 + wo*32 + j*16 + lm;
        #pragma unroll
        for (int r=0;r<4;++r){
          int row = n0 + wn*64 + i*16 + quad*4 + r;
          float v = acc[i][j][r];
          Y[(size_t)row*Cx + oc] = f2b(v);
          if (j==0){ s0+=v; q0+=v*v; } else { s1+=v; q1+=v*v; }
        }
      }
    }
    s0 += __shfl_xor(s0,16); s0 += __shfl_xor(s0,32);
    q0 += __shfl_xor(q0,16); q0 += __shfl_xor(q0,32);
    s1 += __shfl_xor(s1,16); s1 += __shfl_xor(s1,32);
    q1 += __shfl_xor(q1,16); q1 += __shfl_xor(q1,32);
    if (tid < 128) ((float*)red)[tid] = 0.0f;
    __syncthreads();
    if (lane < 16){
      atomicAdd(&red[wo*2+0][lm][0], s0);
      atomicAdd(&red[wo*2+0][lm][1], q0);
      atomicAdd(&red[wo*2+1][lm][0], s1);
      atomicAdd(&red[wo*2+1][lm][1], q1);
    }
    __syncthreads();
    if (tid < 4){
      float ss=0, qq=0;
      #pragma unroll
      for (int k=0;k<16;++k){ ss += red[tid][k][0]; qq += red[tid][k][1]; }
      int g = (o0 >> 4) + tid;
      atomicAdd(&stats[(b*Gx + g)*2 + 0], ss);
      atomicAdd(&stats[(b*Gx + g)*2 + 1], qq);
    }
  }
}

// ---------------- stats -> mu, rstd ----------------
__global__ void k_finalize(const float* __restrict__ st, float* __restrict__ mr){
  int i = threadIdx.x;   // 256 = 16b x 16g
  float s = st[i*2+0], q = st[i*2+1];
  float mu  = s * (1.0f/GRPN);
  float var = q * (1.0f/GRPN) - mu*mu;
  mr[i*2+0] = mu;
  mr[i*2+1] = rsqrtf(var + 1e-5f);
}

// ---------------- elementwise GN-apply + SiLU (bf16 in/out, fp32 params) ----------------
__global__ __launch_bounds__(256) void k_norm_silu(const u16* __restrict__ Yin, u16* __restrict__ Xp,
    const float* __restrict__ mr, const float* __restrict__ gw, const float* __restrict__ gb){
  size_t e8 = ((size_t)blockIdx.x*256 + threadIdx.x)*8;
  int c = (int)(e8 & 255);
  int b = (int)(e8 / ((size_t)HWx*Cx));
  int g = c >> 4;
  float mu = mr[(b*Gx+g)*2], rs = mr[(b*Gx+g)*2+1];
  us8 v = *(const us8*)&Yin[e8];
  us8 o;
  #pragma unroll
  for (int k=0;k<8;++k){
    float xn = (b2f(v[k]) - mu)*rs*gw[c+k] + gb[c+k];
    o[k] = f2b(xn * sigm(xn));
  }
  *(us8*)&Xp[e8] = o;
}

// ---------------- W-direction scans (lr + rl) -> S ----------------
__global__ __launch_bounds__(128) void k_scan_w(const u16* __restrict__ Xp, u16* __restrict__ S,
    const float* __restrict__ ap, const float* __restrict__ bp, const float* __restrict__ cpr, const float* __restrict__ dp){
  __shared__ u16 ins[96*128];
  __shared__ u16 accs[96*128];
  int blk = blockIdx.x;
  int ch = blk & 1;
  int row = blk >> 1;
  int h = row % Hx, b = row / Hx;
  int t = threadIdx.x;
  int c = ch*128 + t;
  float A0 = sigm(ap[c]),      B0 = bp[c],      C0 = cpr[c],      D0 = dp[c];
  float A1 = sigm(ap[Cx+c]),   B1 = bp[Cx+c],   C1 = cpr[Cx+c],   D1 = dp[Cx+c];
  const u16* base = Xp + ((size_t)(b*Hx + h)*Wx)*Cx + c;
  for (int w=0; w<Wx; ++w) ins[w*128+t] = base[(size_t)w*Cx];
  float hs = 0.0f;
  #pragma unroll 4
  for (int w=0; w<Wx; ++w){
    float xv = b2f(ins[w*128+t]);
    hs = A0*hs + B0*xv;
    accs[w*128+t] = f2b(C0*hs + D0*xv);
  }
  hs = 0.0f;
  u16* sb = S + ((size_t)(b*Hx + h)*Wx)*Cx + c;
  #pragma unroll 4
  for (int w=Wx-1; w>=0; --w){
    float xv = b2f(ins[w*128+t]);
    hs = A1*hs + B1*xv;
    sb[(size_t)w*Cx] = f2b(C1*hs + D1*xv + b2f(accs[w*128+t]));
  }
}

// ---------------- H-direction scans (tb + bt), accumulate into S ----------------
__global__ __launch_bounds__(128) void k_scan_h(const u16* __restrict__ Xp, u16* __restrict__ S,
    const float* __restrict__ ap, const float* __restrict__ bp, const float* __restrict__ cpr, const float* __restrict__ dp){
  __shared__ u16 ins[96*128];
  __shared__ u16 accs[96*128];
  int blk = blockIdx.x;
  int ch = blk & 1;
  int col = blk >> 1;
  int w = col % Wx, b = col / Wx;
  int t = threadIdx.x;
  int c = ch*128 + t;
  float A2 = sigm(ap[2*Cx+c]), B2 = bp[2*Cx+c], C2 = cpr[2*Cx+c], D2 = dp[2*Cx+c];
  float A3 = sigm(ap[3*Cx+c]), B3 = bp[3*Cx+c], C3 = cpr[3*Cx+c], D3 = dp[3*Cx+c];
  const u16* base = Xp + ((size_t)(b*Hx)*Wx + w)*Cx + c;
  for (int h=0; h<Hx; ++h) ins[h*128+t] = base[(size_t)h*Wx*Cx];
  float hs = 0.0f;
  #pragma unroll 4
  for (int h=0; h<Hx; ++h){
    float xv = b2f(ins[h*128+t]);
    hs = A2*hs + B2*xv;
    accs[h*128+t] = f2b(C2*hs + D2*xv);
  }
  hs = 0.0f;
  u16* sb = S + ((size_t)(b*Hx)*Wx + w)*Cx + c;
  #pragma unroll 4
  for (int h=Hx-1; h>=0; --h){
    float xv = b2f(ins[h*128+t]);
    hs = A3*hs + B3*xv;
    size_t off = (size_t)h*Wx*Cx;
    sb[off] = f2b(C3*hs + D3*xv + b2f(accs[h*128+t]) + b2f(sb[off]));
  }
}

// ---------------- depthwise 3x3, channels-last (bf16 act, fp32 weights) ----------------
// Each thread: 4 consecutive w outputs x 4 channels. Weights in REGISTERS (no in-loop LDS
// reads -> kills the 8-way bank conflict that was ~48% of this kernel's cycles).
// Input patch (3 rows x 6 cols) loaded/converted once and reused across the 4 outputs.
__global__ __launch_bounds__(256) void k_dwconv(const u16* __restrict__ F, const float* __restrict__ dwW, u16* __restrict__ O){
  __shared__ float wl[2304];
  int t = threadIdx.x;
  #pragma unroll
  for (int i=0;i<9;++i) wl[t + i*256] = dwW[t + i*256];
  __syncthreads();
  int blk = blockIdx.x;
  int w16 = blk % (Wx/16);
  int h   = (blk/(Wx/16)) % Hx;
  int b   = blk / ((Wx/16)*Hx);
  int cq = (t & 63) << 2;            // channel quad base (lane-major -> 512B coalesced)
  int w0 = (w16 << 4) + ((t >> 6) << 2);  // 4 outputs per thread, wave-uniform
  // per-thread weights: 36 contiguous floats = wl[cq*9 .. cq*9+35]
  float wt[36];
  #pragma unroll
  for (int j=0;j<9;++j) *(float4_*)&wt[4*j] = *(const float4_*)&wl[cq*9 + 4*j];
  float acc[4][4];
  #pragma unroll
  for (int ow=0;ow<4;++ow){ acc[ow][0]=0.0f; acc[ow][1]=0.0f; acc[ow][2]=0.0f; acc[ow][3]=0.0f; }
  const u16* Fb = F + ((size_t)(b*Hx)*Wx)*Cx + cq;
  #pragma unroll
  for (int ky=0; ky<3; ++ky){
    int hh = h + ky - 1;
    if (hh < 0 || hh >= Hx) continue;
    #pragma unroll
    for (int j=0; j<6; ++j){            // input cols w0-1 .. w0+4
      int ww = w0 + j - 1;
      if (ww < 0 || ww >= Wx) continue;
      us4 v = *(const us4*)&Fb[((size_t)hh*Wx + ww)*Cx];
      float f0=b2f(v[0]), f1=b2f(v[1]), f2=b2f(v[2]), f3=b2f(v[3]);
      // input col (w0+j-1) feeds output (w0+ow) with kx = j-ow, kx in [0,2]
      #pragma unroll
      for (int ow = (j-2<0?0:j-2); ow <= (j<3?j:3); ++ow){
        int kidx = ky*3 + (j - ow);
        acc[ow][0] += f0 * wt[0*9 + kidx];
        acc[ow][1] += f1 * wt[1*9 + kidx];
        acc[ow][2] += f2 * wt[2*9 + kidx];
        acc[ow][3] += f3 * wt[3*9 + kidx];
      }
    }
  }
  #pragma unroll
  for (int ow=0; ow<4; ++ow){
    us4 o = { f2b(acc[ow][0]), f2b(acc[ow][1]), f2b(acc[ow][2]), f2b(acc[ow][3]) };
    *(us4*)&O[((size_t)((b*Hx+h)*Wx) + w0 + ow)*Cx + cq] = o;
  }
}

// ---------------- GN-apply + SiLU + transpose back to [b,c,hw] (fp32 out) ----------------
__global__ __launch_bounds__(256) void k_norm_tr(const u16* __restrict__ Y3, float* __restrict__ Out,
    const float* __restrict__ mr, const float* __restrict__ gw, const float* __restrict__ gb){
  __shared__ float tile[32][36];   // [hw][c]
  int blk = blockIdx.x;
  int ct  = blk & 7;
  int hwt = (blk >> 3) % 288;
  int b   = blk / 2304;
  int c0 = ct*32, hw0 = hwt*32;
  int t = threadIdx.x;
  int r  = t >> 3;
  int q4 = (t & 7) << 2;
  us4 v = *(const us4*)&Y3[((size_t)(b*HWx + hw0 + r))*Cx + c0 + q4];
  int g = (c0 + q4) >> 4;
  float mu = mr[(b*Gx+g)*2], rs = mr[(b*Gx+g)*2+1];
  #pragma unroll
  for (int i=0;i<4;++i){
    float xn = (b2f(v[i]) - mu)*rs*gw[c0+q4+i] + gb[c0+q4+i];
    tile[r][q4+i] = xn * sigm(xn);
  }
  __syncthreads();
  float4_ o = { tile[q4+0][r], tile[q4+1][r], tile[q4+2][r], tile[q4+3][r] };
  *(float4_*)&Out[((size_t)(b*Cx + c0 + r))*HWx + hw0 + q4] = o;
}

extern "C" void kernel_launch(void* const* d_in, const int* in_sizes, int n_in,
                              void* d_out, int out_size, void* d_ws, size_t ws_size,
                              hipStream_t stream){
  (void)in_sizes; (void)n_in; (void)out_size; (void)ws_size;
  const float* x    = (const float*)d_in[0];
  const float* in_w = (const float*)d_in[1];
  const float* gn1w = (const float*)d_in[2];
  const float* gn1b = (const float*)d_in[3];
  const float* ap   = (const float*)d_in[4];
  const float* bp   = (const float*)d_in[5];
  const float* cp   = (const float*)d_in[6];
  const float* dp   = (const float*)d_in[7];
  const float* gw   = (const float*)d_in[8];
  const float* gb   = (const float*)d_in[9];
  const float* dww  = (const float*)d_in[10];
  const float* pww  = (const float*)d_in[11];
  const float* gn2w = (const float*)d_in[12];
  const float* gn2b = (const float*)d_in[13];
  float* out = (float*)d_out;
  char* ws = (char*)d_ws;
  const size_t NB = (size_t)NTOK * Cx * 2;   // 75,497,472 bytes per bf16 tensor
  u16* xT = (u16*)(ws);            // also reused for dwconv output
  u16* y1 = (u16*)(ws + NB);       // also reused for GEMM3 output
  u16* xp = (u16*)(ws + 2*NB);
  u16* S  = (u16*)(ws + 3*NB);     // scan sum -> fused (in-place)
  float* stats1 = (float*)(ws + 4*NB);
  float* stats2 = stats1 + 512;
  float* mr1    = stats1 + 1024;
  float* mr2    = stats1 + 1536;

  hipMemsetAsync(stats1, 0, 1024*sizeof(float), stream);

  k_transpose<<<36864, 256, 0, stream>>>(x, xT);
  k_gemm<0><<<dim3(NTOK/BM, Cx/BN), 256, 0, stream>>>(xT, in_w, y1, stats1, nullptr, nullptr);
  k_finalize<<<1, 256, 0, stream>>>(stats1, mr1);
  k_norm_silu<<<NTOK*Cx/2048, 256, 0, stream>>>(y1, xp, mr1, gn1w, gn1b);
  k_scan_w<<<Bx*Hx*2, 128, 0, stream>>>(xp, S, ap, bp, cp, dp);
  k_scan_h<<<Bx*Wx*2, 128, 0, stream>>>(xp, S, ap, bp, cp, dp);
  k_gemm<1><<<dim3(NTOK/BM, Cx/BN), 256, 0, stream>>>(xp, gw, S, nullptr, gb, S);
  k_dwconv<<<Bx*Hx*(Wx/16), 256, 0, stream>>>(S, dww, xT);
  k_gemm<0><<<dim3(NTOK/BM, Cx/BN), 256, 0, stream>>>(xT, pww, y1, stats2, nullptr, nullptr);
  k_finalize<<<1, 256, 0, stream>>>(stats2, mr2);
  k_norm_tr<<<36864, 256, 0, stream>>>(y1, out, mr2, gn2w, gn2b);
}

// Round 2
// 752.635 us; speedup vs baseline: 1.0379x; 1.0143x over previous
//
#include <hip/hip_runtime.h>
#include <hip/hip_bf16.h>

#define Bx 16
#define Cx 256
#define Hx 96
#define Wx 96
#define HWx 9216
#define NTOK 147456
#define Gx 16
#define GRPN 147456.0f

typedef unsigned short u16;
typedef unsigned int u32;
typedef __attribute__((ext_vector_type(8))) short short8;
typedef __attribute__((ext_vector_type(4))) float float4_;
typedef __attribute__((ext_vector_type(4))) unsigned short us4;
typedef __attribute__((ext_vector_type(8))) unsigned short us8;
typedef __attribute__((ext_vector_type(4))) unsigned int ui4;

__device__ __forceinline__ float b2f(u16 u){ u32 x = ((u32)u)<<16; float f; __builtin_memcpy(&f,&x,4); return f; }
__device__ __forceinline__ u16 f2b(float f){ u32 x; __builtin_memcpy(&x,&f,4); x += 0x7FFFu + ((x>>16)&1u); return (u16)(x>>16); }
__device__ __forceinline__ float sigm(float v){ return 1.0f/(1.0f+__expf(-v)); }

// ---------------- transpose x[b,c,hw] (fp32) -> xT[b,hw,c] (bf16) ----------------
__global__ __launch_bounds__(256) void k_transpose(const float* __restrict__ X, u16* __restrict__ XT){
  __shared__ u16 tile[32][36];
  int blk = blockIdx.x;
  int ct  = blk & 7;
  int hwt = (blk >> 3) % 288;
  int b   = blk / 2304;
  int c0 = ct*32, hw0 = hwt*32;
  int t = threadIdx.x;
  int r  = t >> 3;            // load: c-row   | store: hw-row
  int q4 = (t & 7) << 2;      // load: hw-off  | store: c-off
  float4_ v = *(const float4_*)&X[((size_t)(b*Cx + c0 + r))*HWx + hw0 + q4];
  tile[r][q4+0]=f2b(v[0]); tile[r][q4+1]=f2b(v[1]); tile[r][q4+2]=f2b(v[2]); tile[r][q4+3]=f2b(v[3]);
  __syncthreads();
  us4 o = { tile[q4+0][r], tile[q4+1][r], tile[q4+2][r], tile[q4+3][r] };
  *(us4*)&XT[((size_t)(b*HWx + hw0 + r))*Cx + c0 + q4] = o;
}

// ---------------- GEMM: Y[n,o] = sum_c A[n,c]*Wm[o,c]  (MFMA bf16, fp32 weights) ----------------
// MODE 0: store bf16 + groupnorm stats atomics. MODE 1: gate epilogue (sigmoid(+bias), fused=0.25*S*gate in-place).
// Grid: 1-D 4608 blocks with bijective XCD-chunk swizzle (4608 %% 8 == 0): each XCD owns a
// contiguous n-range with all 4 o-tiles adjacent -> A-panel fetched ~once (was up to 4x).
#define BM 128
#define BN 64
#define LDA 40
#define LDB 264

template<int MODE>
__global__ __launch_bounds__(256) void k_gemm(const u16* __restrict__ A,
                                              const float* __restrict__ Wm,
                                              u16* __restrict__ Y,
                                              float* __restrict__ stats,
                                              const float* __restrict__ bias,
                                              u16* __restrict__ Sb)
{
  __shared__ u16 Ws[BN*LDB];
  __shared__ u16 As[BM*LDA];
  __shared__ float red[4][16][2];
  const int tid = threadIdx.x;
  int lin = blockIdx.x;
  int swz = (lin & 7) * 576 + (lin >> 3);   // 4608/8 chunks; o fastest within chunk
  const int n0 = (swz >> 2) * BM;
  const int o0 = (swz & 3) * BN;
  // W panel (64 x 256) resident for whole K loop: fp32 -> bf16 convert on stage
  #pragma unroll
  for (int it=0; it<16; ++it){
    int cid = tid + it*256;        // 0..4095
    int row = cid >> 6;            // 0..63
    int ko  = (cid & 63) << 2;     // 0..252 step 4
    float4_ w4 = *(const float4_*)&Wm[(size_t)(o0+row)*Cx + ko];
    us4 wb = { f2b(w4[0]), f2b(w4[1]), f2b(w4[2]), f2b(w4[3]) };
    *(us4*)&Ws[row*LDB + ko] = wb;
  }
  const int lane = tid & 63;
  const int wid  = tid >> 6;
  const int lm   = lane & 15;
  const int quad = lane >> 4;
  const int wn = wid & 1;     // n offset 0/64
  const int wo = wid >> 1;    // o offset 0/32
  float4_ acc[4][2];
  #pragma unroll
  for (int i=0;i<4;++i){ acc[i][0] = (float4_)0.0f; acc[i][1] = (float4_)0.0f; }
  for (int kk=0; kk<Cx; kk+=32){
    __syncthreads();
    #pragma unroll
    for (int it=0; it<2; ++it){
      int cid = tid + it*256;
      int r = cid >> 2;
      int ko = (cid & 3) << 3;
      *(ui4*)&As[r*LDA + ko] = *(const ui4*)&A[(size_t)(n0+r)*Cx + kk + ko];
    }
    __syncthreads();
    short8 af[4], bf[2];
    #pragma unroll
    for (int i=0;i<4;++i) af[i] = *(const short8*)&As[(wn*64 + i*16 + lm)*LDA + quad*8];
    #pragma unroll
    for (int j=0;j<2;++j) bf[j] = *(const short8*)&Ws[(wo*32 + j*16 + lm)*LDB + kk + quad*8];
    #pragma unroll
    for (int i=0;i<4;++i)
      #pragma unroll
      for (int j=0;j<2;++j)
        acc[i][j] = __builtin_amdgcn_mfma_f32_16x16x32_bf16(af[i], bf[j], acc[i][j], 0, 0, 0);
  }
  const int b = n0 / HWx;
  if (MODE == 1){
    #pragma unroll
    for (int i=0;i<4;++i){
      #pragma unroll
      for (int j=0;j<2;++j){
        int oc = o0 + wo*32 + j*16 + lm;
        float bb = bias[oc];
        #pragma unroll
        for (int r=0;r<4;++r){
          int row = n0 + wn*64 + i*16 + quad*4 + r;
          size_t idx = (size_t)row*Cx + oc;
          float g = sigm(acc[i][j][r] + bb);
          Y[idx] = f2b(0.25f * b2f(Sb[idx]) * g);
        }
      }
    }
  } else {
    float s0=0,s1=0,q0=0,q1=0;
    #pragma unroll
    for (int i=0;i<4;++i){
      #pragma unroll
      for (int j=0;j<2;++j){
        int oc = o0 + wo*32 + j*16 + lm;
        #pragma unroll
        for (int r=0;r<4;++r){
          int row = n0 + wn*64 + i*16 + quad*4 + r;
          float v = acc[i][j][r];
          Y[(size_t)row*Cx + oc] = f2b(v);
          if (j==0){ s0+=v; q0+=v*v; } else { s1+=v; q1+=v*v; }
        }
      }
    }
    s0 += __shfl_xor(s0,16); s0 += __shfl_xor(s0,32);
    q0 += __shfl_xor(q0,16); q0 += __shfl_xor(q0,32);
    s1 += __shfl_xor(s1,16); s1 += __shfl_xor(s1,32);
    q1 += __shfl_xor(q1,16); q1 += __shfl_xor(q1,32);
    if (tid < 128) ((float*)red)[tid] = 0.0f;
    __syncthreads();
    if (lane < 16){
      atomicAdd(&red[wo*2+0][lm][0], s0);
      atomicAdd(&red[wo*2+0][lm][1], q0);
      atomicAdd(&red[wo*2+1][lm][0], s1);
      atomicAdd(&red[wo*2+1][lm][1], q1);
    }
    __syncthreads();
    if (tid < 4){
      float ss=0, qq=0;
      #pragma unroll
      for (int k=0;k<16;++k){ ss += red[tid][k][0]; qq += red[tid][k][1]; }
      int g = (o0 >> 4) + tid;
      atomicAdd(&stats[(b*Gx + g)*2 + 0], ss);
      atomicAdd(&stats[(b*Gx + g)*2 + 1], qq);
    }
  }
}

// ---------------- stats -> mu, rstd ----------------
__global__ void k_finalize(const float* __restrict__ st, float* __restrict__ mr){
  int i = threadIdx.x;   // 256 = 16b x 16g
  float s = st[i*2+0], q = st[i*2+1];
  float mu  = s * (1.0f/GRPN);
  float var = q * (1.0f/GRPN) - mu*mu;
  mr[i*2+0] = mu;
  mr[i*2+1] = rsqrtf(var + 1e-5f);
}

// ---------------- W-direction scans (lr + rl) -> S, with fused GN1+SiLU ----------------
// Reads RAW gemm output y1, applies groupnorm+silu on load (same bf16 rounding point as the
// old standalone k_norm_silu), stores normed activation to xp (for scan_h / gate gemm) and
// runs both w-direction scans.
__global__ __launch_bounds__(128) void k_scan_w(const u16* __restrict__ Y1, u16* __restrict__ Xp, u16* __restrict__ S,
    const float* __restrict__ ap, const float* __restrict__ bp, const float* __restrict__ cpr, const float* __restrict__ dp,
    const float* __restrict__ mr, const float* __restrict__ gwv, const float* __restrict__ gbv){
  __shared__ u16 ins[96*128];
  __shared__ u16 accs[96*128];
  int blk = blockIdx.x;
  int ch = blk & 1;
  int row = blk >> 1;
  int h = row % Hx, b = row / Hx;
  int t = threadIdx.x;
  int c = ch*128 + t;
  float A0 = sigm(ap[c]),      B0 = bp[c],      C0 = cpr[c],      D0 = dp[c];
  float A1 = sigm(ap[Cx+c]),   B1 = bp[Cx+c],   C1 = cpr[Cx+c],   D1 = dp[Cx+c];
  int g = c >> 4;
  float mu = mr[(b*Gx+g)*2], rs = mr[(b*Gx+g)*2+1];
  float gwc = gwv[c], gbc = gbv[c];
  const u16* base = Y1 + ((size_t)(b*Hx + h)*Wx)*Cx + c;
  u16* xpb = Xp + ((size_t)(b*Hx + h)*Wx)*Cx + c;
  for (int w=0; w<Wx; ++w){
    float xn = (b2f(base[(size_t)w*Cx]) - mu)*rs*gwc + gbc;
    u16 v = f2b(xn * sigm(xn));
    ins[w*128+t] = v;
    xpb[(size_t)w*Cx] = v;
  }
  float hs = 0.0f;
  #pragma unroll 4
  for (int w=0; w<Wx; ++w){
    float xv = b2f(ins[w*128+t]);
    hs = A0*hs + B0*xv;
    accs[w*128+t] = f2b(C0*hs + D0*xv);
  }
  hs = 0.0f;
  u16* sb = S + ((size_t)(b*Hx + h)*Wx)*Cx + c;
  #pragma unroll 4
  for (int w=Wx-1; w>=0; --w){
    float xv = b2f(ins[w*128+t]);
    hs = A1*hs + B1*xv;
    sb[(size_t)w*Cx] = f2b(C1*hs + D1*xv + b2f(accs[w*128+t]));
  }
}

// ---------------- H-direction scans (tb + bt), accumulate into S ----------------
__global__ __launch_bounds__(128) void k_scan_h(const u16* __restrict__ Xp, u16* __restrict__ S,
    const float* __restrict__ ap, const float* __restrict__ bp, const float* __restrict__ cpr, const float* __restrict__ dp){
  __shared__ u16 ins[96*128];
  __shared__ u16 accs[96*128];
  int blk = blockIdx.x;
  int ch = blk & 1;
  int col = blk >> 1;
  int w = col % Wx, b = col / Wx;
  int t = threadIdx.x;
  int c = ch*128 + t;
  float A2 = sigm(ap[2*Cx+c]), B2 = bp[2*Cx+c], C2 = cpr[2*Cx+c], D2 = dp[2*Cx+c];
  float A3 = sigm(ap[3*Cx+c]), B3 = bp[3*Cx+c], C3 = cpr[3*Cx+c], D3 = dp[3*Cx+c];
  const u16* base = Xp + ((size_t)(b*Hx)*Wx + w)*Cx + c;
  for (int h=0; h<Hx; ++h) ins[h*128+t] = base[(size_t)h*Wx*Cx];
  float hs = 0.0f;
  #pragma unroll 4
  for (int h=0; h<Hx; ++h){
    float xv = b2f(ins[h*128+t]);
    hs = A2*hs + B2*xv;
    accs[h*128+t] = f2b(C2*hs + D2*xv);
  }
  hs = 0.0f;
  u16* sb = S + ((size_t)(b*Hx)*Wx + w)*Cx + c;
  #pragma unroll 4
  for (int h=Hx-1; h>=0; --h){
    float xv = b2f(ins[h*128+t]);
    hs = A3*hs + B3*xv;
    size_t off = (size_t)h*Wx*Cx;
    sb[off] = f2b(C3*hs + D3*xv + b2f(accs[h*128+t]) + b2f(sb[off]));
  }
}

// ---------------- depthwise 3x3, channels-last (bf16 act, fp32 weights) ----------------
// Weights in registers; 4 w-outputs x 4 channels per thread; input patch reused across outputs.
__global__ __launch_bounds__(256) void k_dwconv(const u16* __restrict__ F, const float* __restrict__ dwW, u16* __restrict__ O){
  __shared__ float wl[2304];
  int t = threadIdx.x;
  #pragma unroll
  for (int i=0;i<9;++i) wl[t + i*256] = dwW[t + i*256];
  __syncthreads();
  int blk = blockIdx.x;
  int w16 = blk % (Wx/16);
  int h   = (blk/(Wx/16)) % Hx;
  int b   = blk / ((Wx/16)*Hx);
  int cq = (t & 63) << 2;            // channel quad base (lane-major -> 512B coalesced)
  int w0 = (w16 << 4) + ((t >> 6) << 2);  // 4 outputs per thread, wave-uniform
  float wt[36];
  #pragma unroll
  for (int j=0;j<9;++j) *(float4_*)&wt[4*j] = *(const float4_*)&wl[cq*9 + 4*j];
  float acc[4][4];
  #pragma unroll
  for (int ow=0;ow<4;++ow){ acc[ow][0]=0.0f; acc[ow][1]=0.0f; acc[ow][2]=0.0f; acc[ow][3]=0.0f; }
  const u16* Fb = F + ((size_t)(b*Hx)*Wx)*Cx + cq;
  #pragma unroll
  for (int ky=0; ky<3; ++ky){
    int hh = h + ky - 1;
    if (hh < 0 || hh >= Hx) continue;
    #pragma unroll
    for (int j=0; j<6; ++j){            // input cols w0-1 .. w0+4
      int ww = w0 + j - 1;
      if (ww < 0 || ww >= Wx) continue;
      us4 v = *(const us4*)&Fb[((size_t)hh*Wx + ww)*Cx];
      float f0=b2f(v[0]), f1=b2f(v[1]), f2=b2f(v[2]), f3=b2f(v[3]);
      #pragma unroll
      for (int ow = (j-2<0?0:j-2); ow <= (j<3?j:3); ++ow){
        int kidx = ky*3 + (j - ow);
        acc[ow][0] += f0 * wt[0*9 + kidx];
        acc[ow][1] += f1 * wt[1*9 + kidx];
        acc[ow][2] += f2 * wt[2*9 + kidx];
        acc[ow][3] += f3 * wt[3*9 + kidx];
      }
    }
  }
  #pragma unroll
  for (int ow=0; ow<4; ++ow){
    us4 o = { f2b(acc[ow][0]), f2b(acc[ow][1]), f2b(acc[ow][2]), f2b(acc[ow][3]) };
    *(us4*)&O[((size_t)((b*Hx+h)*Wx) + w0 + ow)*Cx + cq] = o;
  }
}

// ---------------- GN-apply + SiLU + transpose back to [b,c,hw] (fp32 out) ----------------
__global__ __launch_bounds__(256) void k_norm_tr(const u16* __restrict__ Y3, float* __restrict__ Out,
    const float* __restrict__ mr, const float* __restrict__ gw, const float* __restrict__ gb){
  __shared__ float tile[32][36];   // [hw][c]
  int blk = blockIdx.x;
  int ct  = blk & 7;
  int hwt = (blk >> 3) % 288;
  int b   = blk / 2304;
  int c0 = ct*32, hw0 = hwt*32;
  int t = threadIdx.x;
  int r  = t >> 3;
  int q4 = (t & 7) << 2;
  us4 v = *(const us4*)&Y3[((size_t)(b*HWx + hw0 + r))*Cx + c0 + q4];
  int g = (c0 + q4) >> 4;
  float mu = mr[(b*Gx+g)*2], rs = mr[(b*Gx+g)*2+1];
  #pragma unroll
  for (int i=0;i<4;++i){
    float xn = (b2f(v[i]) - mu)*rs*gw[c0+q4+i] + gb[c0+q4+i];
    tile[r][q4+i] = xn * sigm(xn);
  }
  __syncthreads();
  float4_ o = { tile[q4+0][r], tile[q4+1][r], tile[q4+2][r], tile[q4+3][r] };
  *(float4_*)&Out[((size_t)(b*Cx + c0 + r))*HWx + hw0 + q4] = o;
}

extern "C" void kernel_launch(void* const* d_in, const int* in_sizes, int n_in,
                              void* d_out, int out_size, void* d_ws, size_t ws_size,
                              hipStream_t stream){
  (void)in_sizes; (void)n_in; (void)out_size; (void)ws_size;
  const float* x    = (const float*)d_in[0];
  const float* in_w = (const float*)d_in[1];
  const float* gn1w = (const float*)d_in[2];
  const float* gn1b = (const float*)d_in[3];
  const float* ap   = (const float*)d_in[4];
  const float* bp   = (const float*)d_in[5];
  const float* cp   = (const float*)d_in[6];
  const float* dp   = (const float*)d_in[7];
  const float* gw   = (const float*)d_in[8];
  const float* gb   = (const float*)d_in[9];
  const float* dww  = (const float*)d_in[10];
  const float* pww  = (const float*)d_in[11];
  const float* gn2w = (const float*)d_in[12];
  const float* gn2b = (const float*)d_in[13];
  float* out = (float*)d_out;
  char* ws = (char*)d_ws;
  const size_t NB = (size_t)NTOK * Cx * 2;   // 75,497,472 bytes per bf16 tensor
  u16* xT = (u16*)(ws);            // also reused for dwconv output
  u16* y1 = (u16*)(ws + NB);       // also reused for GEMM3 output
  u16* xp = (u16*)(ws + 2*NB);
  u16* S  = (u16*)(ws + 3*NB);     // scan sum -> fused (in-place)
  float* stats1 = (float*)(ws + 4*NB);
  float* stats2 = stats1 + 512;
  float* mr1    = stats1 + 1024;
  float* mr2    = stats1 + 1536;

  hipMemsetAsync(stats1, 0, 1024*sizeof(float), stream);

  k_transpose<<<36864, 256, 0, stream>>>(x, xT);
  k_gemm<0><<<4608, 256, 0, stream>>>(xT, in_w, y1, stats1, nullptr, nullptr);
  k_finalize<<<1, 256, 0, stream>>>(stats1, mr1);
  k_scan_w<<<Bx*Hx*2, 128, 0, stream>>>(y1, xp, S, ap, bp, cp, dp, mr1, gn1w, gn1b);
  k_scan_h<<<Bx*Wx*2, 128, 0, stream>>>(xp, S, ap, bp, cp, dp);
  k_gemm<1><<<4608, 256, 0, stream>>>(xp, gw, S, nullptr, gb, S);
  k_dwconv<<<Bx*Hx*(Wx/16), 256, 0, stream>>>(S, dww, xT);
  k_gemm<0><<<4608, 256, 0, stream>>>(xT, pww, y1, stats2, nullptr, nullptr);
  k_finalize<<<1, 256, 0, stream>>>(stats2, mr2);
  k_norm_tr<<<36864, 256, 0, stream>>>(y1, out, mr2, gn2w, gn2b);
}